// Round 1
// baseline (20774.313 us; speedup 1.0000x reference)
//
#include <hip/hip_runtime.h>
#include <hip/hip_cooperative_groups.h>

namespace cg = cooperative_groups;

#define HH 1024
#define BB 128
#define TT 400
#define SS 64
#define CC 8

constexpr int   N_EXC     = 819;          // int(1024*0.8)
constexpr float DT_SEC    = 0.02f;
constexpr float ALPHA_N   = 0.2f;         // DT/TAU_N = 20/100
constexpr float NOISE_STD = 0.05f;

// ---------------- K1: effective recurrent weights -----------------
// W[i][j] = sign(i) * relu(w_rec[i][j]) * (i != j), sign = +1 if i<N_EXC else -1
__global__ void build_w_kernel(const float* __restrict__ w_rec, float* __restrict__ W) {
    int idx = blockIdx.x * 256 + threadIdx.x;
    int i = idx >> 10;
    int j = idx & (HH - 1);
    float w = w_rec[idx];
    w = w > 0.0f ? w : 0.0f;
    float s = (i < N_EXC) ? 1.0f : -1.0f;
    W[idx] = (i == j) ? 0.0f : s * w;
}

// ---------------- K2: feed-forward drive into acts region [B][T][H] ----
#define TCH 16
__global__ void drive_kernel(const float* __restrict__ stim, const float* __restrict__ ctx,
                             const float* __restrict__ w_in, const float* __restrict__ w_ctx,
                             float* __restrict__ drive) {
    int b  = blockIdx.x / (TT / TCH);
    int tc = blockIdx.x % (TT / TCH);
    int t0 = tc * TCH;
    __shared__ float sbuf[TCH][SS + CC];   // 16 x 72 floats, rows 288B (16B aligned)
    int tid = threadIdx.x;
    for (int idx = tid; idx < TCH * SS; idx += 256) {
        int k = idx >> 6, s2 = idx & 63;
        sbuf[k][s2] = stim[((size_t)b * TT + t0 + k) * SS + s2];
    }
    for (int idx = tid; idx < TCH * CC; idx += 256) {
        int k = idx >> 3, c2 = idx & 7;
        sbuf[k][SS + c2] = ctx[((size_t)b * TT + t0 + k) * CC + c2];
    }
    __syncthreads();
    for (int h = tid; h < HH; h += 256) {
        float acc[TCH];
        #pragma unroll
        for (int k = 0; k < TCH; ++k) acc[k] = 0.0f;
        const float4* wr = (const float4*)(w_in + (size_t)h * SS);
        #pragma unroll
        for (int s4 = 0; s4 < SS / 4; ++s4) {
            float4 w = wr[s4];
            #pragma unroll
            for (int k = 0; k < TCH; ++k) {
                float4 a = *(const float4*)(&sbuf[k][s4 * 4]);
                acc[k] += w.x * a.x + w.y * a.y + w.z * a.z + w.w * a.w;
            }
        }
        const float4* wc = (const float4*)(w_ctx + (size_t)h * CC);
        #pragma unroll
        for (int c4 = 0; c4 < CC / 4; ++c4) {
            float4 w = wc[c4];
            #pragma unroll
            for (int k = 0; k < TCH; ++k) {
                float4 a = *(const float4*)(&sbuf[k][SS + c4 * 4]);
                acc[k] += w.x * a.x + w.y * a.y + w.z * a.z + w.w * a.w;
            }
        }
        #pragma unroll
        for (int k = 0; k < TCH; ++k)
            drive[((size_t)b * TT + t0 + k) * HH + h] = acc[k];
    }
}

// ---------------- K3: persistent cooperative scan -----------------
// 256 blocks = 32 j-tiles x 8 batch-tiles. Thread owns (j, b0) and (j, b1),
// keeps h/sx/su in registers for all 400 steps. One grid.sync per step with
// parity-double-buffered h_post in global scratch.
__global__ void __launch_bounds__(256, 1)
rnn_main_kernel(const float* __restrict__ W, const float* __restrict__ noise,
                const float* __restrict__ b_rec, float* acts_drive,
                float* __restrict__ hp_buf) {
    const int bid  = blockIdx.x;
    const int jb   = bid & 31, bb = bid >> 5;
    const int tid  = threadIdx.x;
    const int jj   = tid & 31, brow = tid >> 5;     // 32 cols x 8 rows
    const int j    = jb * 32 + jj;
    const int b0   = bb * 16 + brow;
    const int b1   = b0 + 8;
    const float ax   = (j & 1) ? (20.0f / 200.0f) : (20.0f / 1500.0f);
    const float Uj   = (j & 1) ? 0.15f : 0.45f;
    const float brec = b_rec[j];

    float h0 = 0.f, sx0 = 1.f, su0 = Uj;
    float h1 = 0.f, sx1 = 1.f, su1 = Uj;

    __shared__ float hp_lds[16 * HH];               // 64 KB: my 16 batches' h_post
    cg::grid_group grid = cg::this_grid();

    for (int t = 0; t < TT; ++t) {
        // --- phase A: STP update (old h), compute h_post, publish ---
        float nsx0 = sx0 + ax * (1.f - sx0) - DT_SEC * su0 * sx0 * h0;
        nsx0 = fminf(fmaxf(nsx0, 0.f), 1.f);
        float nsu0 = su0 + ax * (Uj - su0) + DT_SEC * Uj * (1.f - su0) * h0;
        nsu0 = fminf(fmaxf(nsu0, 0.f), 1.f);
        float hp0 = nsu0 * nsx0 * h0;
        sx0 = nsx0; su0 = nsu0;

        float nsx1 = sx1 + ax * (1.f - sx1) - DT_SEC * su1 * sx1 * h1;
        nsx1 = fminf(fmaxf(nsx1, 0.f), 1.f);
        float nsu1 = su1 + ax * (Uj - su1) + DT_SEC * Uj * (1.f - su1) * h1;
        nsu1 = fminf(fmaxf(nsu1, 0.f), 1.f);
        float hp1 = nsu1 * nsx1 * h1;
        sx1 = nsx1; su1 = nsu1;

        float* hpb = hp_buf + (size_t)(t & 1) * BB * HH;
        hpb[b0 * HH + j] = hp0;
        hpb[b1 * HH + j] = hp1;

        grid.sync();

        // --- phase B: stage my 16 batches of h_post into LDS ---
        {
            const float4* src = (const float4*)(hp_buf + (size_t)(t & 1) * BB * HH
                                                + (size_t)bb * 16 * HH);
            float4* dst = (float4*)hp_lds;
            #pragma unroll
            for (int r = 0; r < 16; ++r) dst[tid + r * 256] = src[tid + r * 256];
        }
        __syncthreads();

        // --- phase C: r[b, j] = sum_i hp[b, i] * W[i, j] ---
        float a00=0.f,a01=0.f,a02=0.f,a03=0.f, a10=0.f,a11=0.f,a12=0.f,a13=0.f;
        const float*  wp  = W + j;
        const float4* ha4 = (const float4*)(hp_lds + brow * HH);
        const float4* hb4 = (const float4*)(hp_lds + (brow + 8) * HH);
        #pragma unroll 4
        for (int i4 = 0; i4 < HH / 4; ++i4) {
            float4 a = ha4[i4];
            float4 b = hb4[i4];
            const float* w4 = wp + (i4 << 12);      // rows 4*i4 .. 4*i4+3
            float w0 = w4[0], w1 = w4[1024], w2 = w4[2048], w3 = w4[3072];
            a00 = fmaf(a.x, w0, a00); a10 = fmaf(b.x, w0, a10);
            a01 = fmaf(a.y, w1, a01); a11 = fmaf(b.y, w1, a11);
            a02 = fmaf(a.z, w2, a02); a12 = fmaf(b.z, w2, a12);
            a03 = fmaf(a.w, w3, a03); a13 = fmaf(b.w, w3, a13);
        }
        float acc0 = (a00 + a01) + (a02 + a03);
        float acc1 = (a10 + a11) + (a12 + a13);

        // --- phase D: neuron update; drive was pre-written at the acts slot ---
        size_t o0 = ((size_t)b0 * TT + t) * HH + j;
        size_t o1 = ((size_t)b1 * TT + t) * HH + j;
        float d0 = acts_drive[o0];
        float d1 = acts_drive[o1];
        float nz0 = noise[((size_t)t * BB + b0) * HH + j];
        float nz1 = noise[((size_t)t * BB + b1) * HH + j];
        float v0 = h0 * (1.f - ALPHA_N) + ALPHA_N * (d0 + acc0 + brec) + NOISE_STD * nz0;
        float v1 = h1 * (1.f - ALPHA_N) + ALPHA_N * (d1 + acc1 + brec) + NOISE_STD * nz1;
        h0 = v0 > 0.f ? v0 : 0.f;
        h1 = v1 > 0.f ? v1 : 0.f;
        acts_drive[o0] = h0;
        acts_drive[o1] = h1;
        // no second sync needed: next step writes the *other* hp parity buffer,
        // whose last readers finished before the sync we already passed.
    }
}

// ---------------- K4: output + classifier projections -----------------
// one wave per (b,t): 9 dots of length 1024 (3 w_out rows + 6 c1 rows), then
// the tiny 3x(2->8) classifier head on lane 0.
__global__ void proj_kernel(const float* __restrict__ acts, const float* __restrict__ w_out,
                            const float* __restrict__ b_out, const float* __restrict__ c1_w,
                            const float* __restrict__ c1_b, const float* __restrict__ c2_w,
                            const float* __restrict__ c2_b, float* __restrict__ out0,
                            float* __restrict__ outp) {
    int gw   = (int)((blockIdx.x * (size_t)blockDim.x + threadIdx.x) >> 6);
    int lane = threadIdx.x & 63;
    if (gw >= BB * TT) return;
    const float4* arow = (const float4*)(acts + (size_t)gw * HH);
    float accs[9];
    #pragma unroll
    for (int r = 0; r < 9; ++r) accs[r] = 0.f;
    #pragma unroll
    for (int k = 0; k < 4; ++k) {
        int idx = lane + (k << 6);
        float4 a = arow[idx];
        #pragma unroll
        for (int r = 0; r < 9; ++r) {
            const float* wbase = (r < 3) ? (w_out + r * HH) : (c1_w + (size_t)(r - 3) * HH);
            float4 w = ((const float4*)wbase)[idx];
            accs[r] += a.x * w.x + a.y * w.y + a.z * w.z + a.w * w.w;
        }
    }
    #pragma unroll
    for (int r = 0; r < 9; ++r) {
        float v = accs[r];
        #pragma unroll
        for (int off = 32; off > 0; off >>= 1) v += __shfl_down(v, off);
        accs[r] = v;
    }
    if (lane == 0) {
        #pragma unroll
        for (int o = 0; o < 3; ++o) out0[(size_t)gw * 3 + o] = accs[o] + b_out[o];
        float z[6];
        #pragma unroll
        for (int q = 0; q < 6; ++q) z[q] = accs[3 + q] + c1_b[q];
        #pragma unroll
        for (int jc = 0; jc < 3; ++jc) {
            #pragma unroll
            for (int o = 0; o < 8; ++o) {
                float p = c2_b[jc * 8 + o];
                p = fmaf(z[jc * 2 + 0], c2_w[(jc * 8 + o) * 2 + 0], p);
                p = fmaf(z[jc * 2 + 1], c2_w[(jc * 8 + o) * 2 + 1], p);
                outp[(size_t)gw * 24 + jc * 8 + o] = p;
            }
        }
    }
}

extern "C" void kernel_launch(void* const* d_in, const int* in_sizes, int n_in,
                              void* d_out, int out_size, void* d_ws, size_t ws_size,
                              hipStream_t stream) {
    const float* stim  = (const float*)d_in[0];
    const float* ctx   = (const float*)d_in[1];
    const float* w_rec = (const float*)d_in[2];
    const float* b_rec = (const float*)d_in[3];
    const float* w_in  = (const float*)d_in[4];
    const float* w_ctx = (const float*)d_in[5];
    const float* w_out = (const float*)d_in[6];
    const float* b_out = (const float*)d_in[7];
    const float* c1_w  = (const float*)d_in[8];
    const float* c1_b  = (const float*)d_in[9];
    const float* c2_w  = (const float*)d_in[10];
    const float* c2_b  = (const float*)d_in[11];
    const float* noise = (const float*)d_in[12];

    float* out0 = (float*)d_out;                       // [B][T][3]
    float* acts = out0 + (size_t)BB * TT * 3;          // [B][T][H] (holds drive pre-scan)
    float* outp = acts + (size_t)BB * TT * HH;         // [B][T][3][8]

    float* W  = (float*)d_ws;                          // 4 MB effective weights
    float* hp = W + (size_t)HH * HH;                   // 2 x 128 x 1024 h_post double buffer

    build_w_kernel<<<HH * HH / 256, 256, 0, stream>>>(w_rec, W);
    drive_kernel<<<BB * (TT / TCH), 256, 0, stream>>>(stim, ctx, w_in, w_ctx, acts);

    void* args[] = { (void*)&W, (void*)&noise, (void*)&b_rec, (void*)&acts, (void*)&hp };
    hipLaunchCooperativeKernel((const void*)rnn_main_kernel, dim3(256), dim3(256),
                               args, 0, stream);

    proj_kernel<<<(BB * TT) / 4, 256, 0, stream>>>(acts, w_out, b_out, c1_w, c1_b,
                                                   c2_w, c2_b, out0, outp);
}

// Round 3
// 16566.432 us; speedup vs baseline: 1.2540x; 1.2540x over previous
//
#include <hip/hip_runtime.h>
#include <hip/hip_cooperative_groups.h>

namespace cg = cooperative_groups;

typedef float v2f __attribute__((ext_vector_type(2)));

#define HH 1024
#define BB 128
#define TT 400
#define SS 64
#define CC 8

constexpr int   N_EXC     = 819;          // int(1024*0.8)
constexpr float DT_SEC    = 0.02f;
constexpr float ALPHA_N   = 0.2f;         // DT/TAU_N
constexpr float NOISE_STD = 0.05f;

// ---------------- K2: feed-forward drive into acts region [B][T][H] ----
#define TCH 16
__global__ void drive_kernel(const float* __restrict__ stim, const float* __restrict__ ctx,
                             const float* __restrict__ w_in, const float* __restrict__ w_ctx,
                             float* __restrict__ drive) {
    int b  = blockIdx.x / (TT / TCH);
    int tc = blockIdx.x % (TT / TCH);
    int t0 = tc * TCH;
    __shared__ float sbuf[TCH][SS + CC];
    int tid = threadIdx.x;
    for (int idx = tid; idx < TCH * SS; idx += 256) {
        int k = idx >> 6, s2 = idx & 63;
        sbuf[k][s2] = stim[((size_t)b * TT + t0 + k) * SS + s2];
    }
    for (int idx = tid; idx < TCH * CC; idx += 256) {
        int k = idx >> 3, c2 = idx & 7;
        sbuf[k][SS + c2] = ctx[((size_t)b * TT + t0 + k) * CC + c2];
    }
    __syncthreads();
    for (int h = tid; h < HH; h += 256) {
        float acc[TCH];
        #pragma unroll
        for (int k = 0; k < TCH; ++k) acc[k] = 0.0f;
        const float4* wr = (const float4*)(w_in + (size_t)h * SS);
        #pragma unroll
        for (int s4 = 0; s4 < SS / 4; ++s4) {
            float4 w = wr[s4];
            #pragma unroll
            for (int k = 0; k < TCH; ++k) {
                float4 a = *(const float4*)(&sbuf[k][s4 * 4]);
                acc[k] += w.x * a.x + w.y * a.y + w.z * a.z + w.w * a.w;
            }
        }
        const float4* wc = (const float4*)(w_ctx + (size_t)h * CC);
        #pragma unroll
        for (int c4 = 0; c4 < CC / 4; ++c4) {
            float4 w = wc[c4];
            #pragma unroll
            for (int k = 0; k < TCH; ++k) {
                float4 a = *(const float4*)(&sbuf[k][SS + c4 * 4]);
                acc[k] += w.x * a.x + w.y * a.y + w.z * a.z + w.w * a.w;
            }
        }
        #pragma unroll
        for (int k = 0; k < TCH; ++k)
            drive[((size_t)b * TT + t0 + k) * HH + h] = acc[k];
    }
}

// ---------------- K3: persistent cooperative scan, W in registers --------
// grid = 256 blocks = 32 j-tiles x 8 batch-tiles (16 batches each) — 1 block/CU,
// the launch config PROVEN co-resident in round 1.
// Compute role: thread (jg=tid&7, ig=tid>>3) owns W[ig*32..+32][jb*32+jg*4..+4]
//   in 128 VGPRs (sign/relu/diag fused at load; i-quad order rotated by
//   (k+ig)&7 so hp LDS broadcast reads are bank-conflict-free).
// State role: thread (sb=tid>>5, jj=tid&31) owns h/sx/su for batches
//   bb*16+sb (pass 0) and bb*16+8+sb (pass 1).
// Per step: one grid.sync, then two 8-batch passes reusing 32KB hp_lds +
// 32KB part (64KB total — within the static-LDS limit, 1 block/CU).
__global__ void __launch_bounds__(256, 1)
rnn_main_kernel(const float* __restrict__ w_rec, const float* __restrict__ noise,
                const float* __restrict__ b_rec, float* acts_drive,
                float* __restrict__ hp_buf) {
    const int bid = blockIdx.x;
    const int jb  = bid & 31;            // 32 j-tiles
    const int bb  = bid >> 5;            // 8 batch-tiles of 16
    const int tid = threadIdx.x;

    const int jg = tid & 7;              // compute: 8 groups x 4 j-cols
    const int ig = tid >> 3;             // compute: 32 groups x 32 i-rows
    const int jj = tid & 31;             // state: column
    const int sb = tid >> 5;             // state: batch-in-pass (0..7)
    const int j  = jb * 32 + jj;

    __shared__ float hp_lds[8 * HH];     // 32 KB (reused by both passes)
    __shared__ float part[32 * 8 * 32];  // 32 KB [ig][b][skewed slot]

    // ---- one-time: W chunk into registers (rotated i-quad order) ----
    v2f wr2[64];
    {
        const int jcol0 = jb * 32 + jg * 4;
        #pragma unroll
        for (int k = 0; k < 8; ++k) {
            const int iq = (k + ig) & 7;
            #pragma unroll
            for (int di = 0; di < 4; ++di) {
                const int i = ig * 32 + iq * 4 + di;
                float4 w = *(const float4*)(w_rec + (size_t)i * HH + jcol0);
                const float s = (i < N_EXC) ? 1.0f : -1.0f;
                w.x = (i == jcol0 + 0) ? 0.0f : s * fmaxf(w.x, 0.0f);
                w.y = (i == jcol0 + 1) ? 0.0f : s * fmaxf(w.y, 0.0f);
                w.z = (i == jcol0 + 2) ? 0.0f : s * fmaxf(w.z, 0.0f);
                w.w = (i == jcol0 + 3) ? 0.0f : s * fmaxf(w.w, 0.0f);
                wr2[(k * 4 + di) * 2 + 0] = (v2f){w.x, w.y};
                wr2[(k * 4 + di) * 2 + 1] = (v2f){w.z, w.w};
            }
        }
    }

    const float ax   = (j & 1) ? (20.0f / 200.0f) : (20.0f / 1500.0f);
    const float Uj   = (j & 1) ? 0.15f : 0.45f;
    const float brec = b_rec[j];
    float hS[2]  = {0.0f, 0.0f};
    float sxS[2] = {1.0f, 1.0f};
    float suS[2] = {Uj, Uj};

    cg::grid_group grid = cg::this_grid();

    for (int t = 0; t < TT; ++t) {
        const size_t par = (size_t)(t & 1) * BB * HH;

        // --- phase A: STP update (old h), publish h_post for both halves ---
        #pragma unroll
        for (int p = 0; p < 2; ++p) {
            const int b = bb * 16 + p * 8 + sb;
            const float h = hS[p];
            float nsx = sxS[p] + ax * (1.0f - sxS[p]) - DT_SEC * suS[p] * sxS[p] * h;
            nsx = fminf(fmaxf(nsx, 0.0f), 1.0f);
            float nsu = suS[p] + ax * (Uj - suS[p]) + DT_SEC * Uj * (1.0f - suS[p]) * h;
            nsu = fminf(fmaxf(nsu, 0.0f), 1.0f);
            sxS[p] = nsx; suS[p] = nsu;
            hp_buf[par + (size_t)b * HH + j] = nsu * nsx * h;
        }

        grid.sync();

        #pragma unroll
        for (int p = 0; p < 2; ++p) {
            const int bbase = bb * 16 + p * 8;
            // --- stage this pass's 8 batches of h_post into LDS ---
            {
                const float4* src = (const float4*)(hp_buf + par + (size_t)bbase * HH);
                float4* dst = (float4*)hp_lds;
                #pragma unroll
                for (int k = 0; k < 8; ++k) dst[tid + k * 256] = src[tid + k * 256];
            }
            const int b = bbase + sb;
            const size_t oa = ((size_t)b * TT + t) * HH + j;
            const float d  = acts_drive[oa];
            const float nz = noise[((size_t)t * BB + b) * HH + j];
            __syncthreads();

            // --- FMA: partials over my 32-row i-chunk, 4 cols, 8 batches ---
            v2f acc[8][2];
            #pragma unroll
            for (int q = 0; q < 8; ++q) { acc[q][0] = (v2f){0.f, 0.f}; acc[q][1] = (v2f){0.f, 0.f}; }
            #pragma unroll
            for (int k = 0; k < 8; ++k) {
                const int iq    = (k + ig) & 7;
                const int ibase = ig * 32 + iq * 4;
                #pragma unroll
                for (int bq = 0; bq < 8; ++bq) {
                    const float4 h4 = *(const float4*)(hp_lds + bq * HH + ibase);
                    const float hv[4] = {h4.x, h4.y, h4.z, h4.w};
                    #pragma unroll
                    for (int di = 0; di < 4; ++di) {
                        const v2f hs = (v2f){hv[di], hv[di]};
                        acc[bq][0] = wr2[(k * 4 + di) * 2 + 0] * hs + acc[bq][0];
                        acc[bq][1] = wr2[(k * 4 + di) * 2 + 1] * hs + acc[bq][1];
                    }
                }
            }

            // --- partials to LDS, skewed by 13*ig (2-way max = free) ---
            {
                const int base = jg * 4 + ig * 13;
                #pragma unroll
                for (int bq = 0; bq < 8; ++bq) {
                    float* row = part + ig * 256 + bq * 32;
                    row[(base + 0) & 31] = acc[bq][0].x;
                    row[(base + 1) & 31] = acc[bq][0].y;
                    row[(base + 2) & 31] = acc[bq][1].x;
                    row[(base + 3) & 31] = acc[bq][1].y;
                }
            }
            __syncthreads();

            // --- reduce 32 i-group partials at the state-owning thread ---
            float r = 0.0f;
            #pragma unroll
            for (int g = 0; g < 32; ++g)
                r += part[g * 256 + sb * 32 + ((jj + g * 13) & 31)];

            // --- phase D: neuron update, write act ---
            const float h = hS[p];
            float v = h * (1.0f - ALPHA_N) + ALPHA_N * (d + r + brec) + NOISE_STD * nz;
            hS[p] = v > 0.0f ? v : 0.0f;
            acts_drive[oa] = hS[p];
            // pass-1 restage of hp_lds is safe: pass-0 FMA reads finished
            // before pass-0's second __syncthreads; pass-1 part writes are
            // after pass-1's post-staging __syncthreads, hence after all
            // pass-0 reduce reads.
        }
        // cross-step WAR on hp_buf handled by parity + grid.sync (see R1/R2
        // analysis); hp_lds/part reuse ordered by grid.sync + pass syncs.
    }
}

// ---------------- K4: output + classifier projections -----------------
__global__ void proj_kernel(const float* __restrict__ acts, const float* __restrict__ w_out,
                            const float* __restrict__ b_out, const float* __restrict__ c1_w,
                            const float* __restrict__ c1_b, const float* __restrict__ c2_w,
                            const float* __restrict__ c2_b, float* __restrict__ out0,
                            float* __restrict__ outp) {
    int gw   = (int)((blockIdx.x * (size_t)blockDim.x + threadIdx.x) >> 6);
    int lane = threadIdx.x & 63;
    if (gw >= BB * TT) return;
    const float4* arow = (const float4*)(acts + (size_t)gw * HH);
    float accs[9];
    #pragma unroll
    for (int r = 0; r < 9; ++r) accs[r] = 0.f;
    #pragma unroll
    for (int k = 0; k < 4; ++k) {
        int idx = lane + (k << 6);
        float4 a = arow[idx];
        #pragma unroll
        for (int r = 0; r < 9; ++r) {
            const float* wbase = (r < 3) ? (w_out + r * HH) : (c1_w + (size_t)(r - 3) * HH);
            float4 w = ((const float4*)wbase)[idx];
            accs[r] += a.x * w.x + a.y * w.y + a.z * w.z + a.w * w.w;
        }
    }
    #pragma unroll
    for (int r = 0; r < 9; ++r) {
        float v = accs[r];
        #pragma unroll
        for (int off = 32; off > 0; off >>= 1) v += __shfl_down(v, off);
        accs[r] = v;
    }
    if (lane == 0) {
        #pragma unroll
        for (int o = 0; o < 3; ++o) out0[(size_t)gw * 3 + o] = accs[o] + b_out[o];
        float z[6];
        #pragma unroll
        for (int q = 0; q < 6; ++q) z[q] = accs[3 + q] + c1_b[q];
        #pragma unroll
        for (int jc = 0; jc < 3; ++jc) {
            #pragma unroll
            for (int o = 0; o < 8; ++o) {
                float p = c2_b[jc * 8 + o];
                p = fmaf(z[jc * 2 + 0], c2_w[(jc * 8 + o) * 2 + 0], p);
                p = fmaf(z[jc * 2 + 1], c2_w[(jc * 8 + o) * 2 + 1], p);
                outp[(size_t)gw * 24 + jc * 8 + o] = p;
            }
        }
    }
}

extern "C" void kernel_launch(void* const* d_in, const int* in_sizes, int n_in,
                              void* d_out, int out_size, void* d_ws, size_t ws_size,
                              hipStream_t stream) {
    const float* stim  = (const float*)d_in[0];
    const float* ctx   = (const float*)d_in[1];
    const float* w_rec = (const float*)d_in[2];
    const float* b_rec = (const float*)d_in[3];
    const float* w_in  = (const float*)d_in[4];
    const float* w_ctx = (const float*)d_in[5];
    const float* w_out = (const float*)d_in[6];
    const float* b_out = (const float*)d_in[7];
    const float* c1_w  = (const float*)d_in[8];
    const float* c1_b  = (const float*)d_in[9];
    const float* c2_w  = (const float*)d_in[10];
    const float* c2_b  = (const float*)d_in[11];
    const float* noise = (const float*)d_in[12];

    float* out0 = (float*)d_out;                       // [B][T][3]
    float* acts = out0 + (size_t)BB * TT * 3;          // [B][T][H] (drive pre-scan)
    float* outp = acts + (size_t)BB * TT * HH;         // [B][T][3][8]

    float* hp = (float*)d_ws;                          // 2 x 128 x 1024 double buffer

    drive_kernel<<<BB * (TT / TCH), 256, 0, stream>>>(stim, ctx, w_in, w_ctx, acts);

    void* args[] = { (void*)&w_rec, (void*)&noise, (void*)&b_rec, (void*)&acts, (void*)&hp };
    hipLaunchCooperativeKernel((const void*)rnn_main_kernel, dim3(256), dim3(256),
                               args, 0, stream);

    proj_kernel<<<(BB * TT) / 4, 256, 0, stream>>>(acts, w_out, b_out, c1_w, c1_b,
                                                   c2_w, c2_b, out0, outp);
}